// Round 2
// baseline (501.999 us; speedup 1.0000x reference)
//
#include <hip/hip_runtime.h>
#include <hip/hip_bf16.h>
#include <stdint.h>

#define Bsz 512
#define Ssz 64
#define Esz 768
#define Dsz 256
#define MROWS (Bsz * Ssz)   // 32768
#define FIN 1024

typedef _Float16 f16;
typedef f16 f16x4 __attribute__((ext_vector_type(4)));
typedef f16 f16x8v __attribute__((ext_vector_type(8)));
typedef float f32x4 __attribute__((ext_vector_type(4)));

// ---------------------------------------------------------------------------
// prep: Wp (3x[256][768] f32) -> f16; corr [256][256] f32 -> corrT f16 [e][d];
//       Wb [64][1024] f32 -> f16 (for the G GEMMs)
__global__ __launch_bounds__(256) void prep(const float* __restrict__ Wp0,
                                            const float* __restrict__ Wp1,
                                            const float* __restrict__ Wp2,
                                            const float* __restrict__ corr,
                                            const float* __restrict__ Wb,
                                            f16* __restrict__ Wph,
                                            f16* __restrict__ corrT,
                                            f16* __restrict__ Wbh) {
    const int t = blockIdx.x * 256 + threadIdx.x;
    if (t < 3 * 196608) {
        const int z = t / 196608, i = t % 196608;
        const float* W = (z == 0) ? Wp0 : (z == 1) ? Wp1 : Wp2;
        Wph[(size_t)z * 196608 + i] = (f16)W[i];
    }
    if (t < 65536) {
        const int d = t >> 8, e = t & 255;
        corrT[e * 256 + d] = (f16)corr[d * 256 + e];
        Wbh[t] = (f16)Wb[t];
    }
}

// ---------------------------------------------------------------------------
// MFMA GEMM: C[m,n] = sum_k A[m,k] * B[n,k]  (B given [N][K] row-major, f16)
// Output f16 [M][256]. Tile 128x128xBK64, 256 threads = 4 waves, wave 64x64.
// Software-pipelined: tile k+1 is prefetched into registers right after the
// second barrier, so the global loads are in flight during the whole compute
// phase; the implicit vmcnt(0) at the NEXT iteration's first __syncthreads is
// exactly where we need the data anyway (before ds_write).
template <bool A_F16, bool BIAS>
__global__ __launch_bounds__(256) void mfma_gemm(
    const float* __restrict__ A32a, const float* __restrict__ A32b,
    const float* __restrict__ A32c, const f16* __restrict__ A16,
    const f16* __restrict__ Bh, const float* __restrict__ biasA,
    const float* __restrict__ biasB, const float* __restrict__ biasC,
    f16* __restrict__ Ch, int K) {
    const int tid = threadIdx.x;
    const int n0 = blockIdx.x * 128;
    const int m0 = blockIdx.y * 128;
    const int z = blockIdx.z;
    const float* A32 = (z == 0) ? A32a : (z == 1) ? A32b : A32c;
    const float* bias = (z == 0) ? biasA : (z == 1) ? biasB : biasC;
    const f16* Bz = Bh + (size_t)z * 256 * K;
    f16* Cz = Ch + (size_t)z * MROWS * 256;

    __shared__ __align__(16) f16 AhS[8192];  // 16 KB
    __shared__ __align__(16) f16 BhS[8192];  // 16 KB

    const int lane = tid & 63;
    const int w = tid >> 6;
    const int ma = (w >> 1) * 4;  // wave's first m-sub (of 8)
    const int nb = (w & 1) * 4;   // wave's first n-sub (of 8)

    // staging decomposition (same every iter)
    const int srow = tid >> 3;      // 0..31 (+32 per rep)
    const int sc8 = tid & 7;        // 0..7

    f32x4 acc[4][4];
#pragma unroll
    for (int i = 0; i < 4; i++)
#pragma unroll
        for (int j = 0; j < 4; j++) acc[i][j] = (f32x4){0.f, 0.f, 0.f, 0.f};

    // prefetch registers (static indexing only)
    float4 alo[4], ahi[4];
    uint4 a16r[4];
    uint4 br[4];

    auto loadk = [&](int kk) {
#pragma unroll
        for (int r = 0; r < 4; r++) {
            const int row = srow + 32 * r;
            if constexpr (A_F16) {
                a16r[r] = *(const uint4*)(A16 + (size_t)(m0 + row) * K + kk + sc8 * 8);
            } else {
                const float* p = A32 + (size_t)(m0 + row) * K + kk + sc8 * 8;
                alo[r] = *(const float4*)p;
                ahi[r] = *(const float4*)(p + 4);
            }
            br[r] = *(const uint4*)(Bz + (size_t)(n0 + row) * K + kk + sc8 * 8);
        }
    };

    loadk(0);

    for (int k0 = 0; k0 < K; k0 += 64) {
        __syncthreads();  // prev compute's LDS reads done (+ drains our prefetch)
#pragma unroll
        for (int r = 0; r < 4; r++) {
            const int row = srow + 32 * r;
            // 16B-unit index, swizzled
            const int unit = (((sc8 >> 2) * 8 + (row >> 4)) * 64 + (row & 15) + 16 * (sc8 & 3)) ^ (sc8 & 3);
            if constexpr (A_F16) {
                *(uint4*)&AhS[unit * 8] = a16r[r];
            } else {
                f16x8v h;
                h[0] = (f16)alo[r].x; h[1] = (f16)alo[r].y; h[2] = (f16)alo[r].z; h[3] = (f16)alo[r].w;
                h[4] = (f16)ahi[r].x; h[5] = (f16)ahi[r].y; h[6] = (f16)ahi[r].z; h[7] = (f16)ahi[r].w;
                *(f16x8v*)&AhS[unit * 8] = h;
            }
            *(uint4*)&BhS[unit * 8] = br[r];
        }
        __syncthreads();
        const int kn = (k0 + 64 < K) ? (k0 + 64) : k0;  // clamp: last iter reloads same tile (harmless)
        loadk(kn);                                      // in flight during compute below
        __builtin_amdgcn_sched_barrier(0);
#pragma unroll
        for (int kh = 0; kh < 2; kh++) {
            f16x8v af[4], bf[4];
#pragma unroll
            for (int i = 0; i < 4; i++)
                af[i] = *(const f16x8v*)&AhS[((((kh * 8 + ma + i) * 64 + lane)) ^ (lane >> 4)) * 8];
#pragma unroll
            for (int j = 0; j < 4; j++)
                bf[j] = *(const f16x8v*)&BhS[((((kh * 8 + nb + j) * 64 + lane)) ^ (lane >> 4)) * 8];
#pragma unroll
            for (int i = 0; i < 4; i++)
#pragma unroll
                for (int j = 0; j < 4; j++)
                    acc[i][j] = __builtin_amdgcn_mfma_f32_16x16x32_f16(af[i], bf[j], acc[i][j], 0, 0, 0);
        }
    }

    // epilogue through LDS for coalesced stores. 128x128 f16 = 32 KB = AhS+BhS.
    f16* Ce = AhS;  // alias both buffers (contiguous by declaration order)
    __syncthreads();  // last fragment reads complete before overwrite
    const int cr = lane & 15, qr = lane >> 4;
    const int mwl = (w >> 1) * 64;
    const int nwl = (w & 1) * 64;
#pragma unroll
    for (int i = 0; i < 4; i++) {
#pragma unroll
        for (int j = 0; j < 4; j++) {
            const int col = nwl + j * 16 + cr;
            const float bv = BIAS ? bias[n0 + col] : 0.f;
#pragma unroll
            for (int r = 0; r < 4; r++) {
                const int row = mwl + i * 16 + qr * 4 + r;
                Ce[row * 128 + col] = (f16)(acc[i][j][r] + bv);
            }
        }
    }
    __syncthreads();
#pragma unroll
    for (int r = 0; r < 8; r++) {
        const int f = r * 256 + tid;
        const int row = f >> 4, c16 = f & 15;
        uint4 v = *(const uint4*)&Ce[row * 128 + c16 * 8];
        *(uint4*)(Cz + (size_t)(m0 + row) * 256 + n0 + c16 * 8) = v;
    }
}

// ---------------------------------------------------------------------------
// Per (b,q): cc[i,j] = sum_e ac[b,i,e]*other[b,j,e] via MFMA (f16 in, f32 acc),
// fragments read directly from global. Then both softmaxes.
// Outputs (f16): aT[q][b][j][i] = softmax_i(cc)[i,j]  (transposed!)
//                oP[q][b][i][j] = softmax_j(cc)[i,j]  (row-major)
__global__ __launch_bounds__(256) void cc_softmax(const f16* __restrict__ ac,
                                                  const f16* __restrict__ proj1,
                                                  const f16* __restrict__ proj2,
                                                  f16* __restrict__ aT,
                                                  f16* __restrict__ oP) {
    const int b = blockIdx.x, q = blockIdx.y;
    const f16* __restrict__ A = ac + (size_t)b * Ssz * Dsz;
    const f16* __restrict__ Bp = (q ? proj2 : proj1) + (size_t)b * Ssz * Dsz;
    __shared__ float sc[64][65];
    __shared__ float cmax[64], csum[64], rmax[64], rsum[64];
    const int tid = threadIdx.x;
    const int lane = tid & 63, w = tid >> 6;
    const int lr = lane & 15;   // row/col within 16-tile (A row, B col)
    const int lk = lane >> 4;   // k-quarter: k = 8*lk + 0..7 within K=32 step

    f32x4 acc[4];
#pragma unroll
    for (int j = 0; j < 4; j++) acc[j] = (f32x4){0.f, 0.f, 0.f, 0.f};

    const f16* __restrict__ Arow = A + (size_t)(w * 16 + lr) * Dsz + lk * 8;
    for (int ks = 0; ks < 8; ks++) {  // K=256 in steps of 32
        f16x8v af = *(const f16x8v*)(Arow + ks * 32);
        f16x8v bf[4];
#pragma unroll
        for (int j = 0; j < 4; j++)
            bf[j] = *(const f16x8v*)(Bp + (size_t)(j * 16 + lr) * Dsz + ks * 32 + lk * 8);
#pragma unroll
        for (int j = 0; j < 4; j++)
            acc[j] = __builtin_amdgcn_mfma_f32_16x16x32_f16(af, bf[j], acc[j], 0, 0, 0);
    }
    // C/D layout: col = lane&15, row = (lane>>4)*4 + r
#pragma unroll
    for (int j = 0; j < 4; j++)
#pragma unroll
        for (int r = 0; r < 4; r++) sc[w * 16 + lk * 4 + r][j * 16 + lr] = acc[j][r];
    __syncthreads();
    if (tid < 64) {
        const int j = tid;
        float m = -1e30f;
        for (int i = 0; i < 64; i++) m = fmaxf(m, sc[i][j]);
        float s = 0.f;
        for (int i = 0; i < 64; i++) s += __expf(sc[i][j] - m);
        cmax[j] = m;
        csum[j] = s;
    } else if (tid < 128) {
        const int i = tid - 64;
        float m = -1e30f;
        for (int j = 0; j < 64; j++) m = fmaxf(m, sc[i][j]);
        float s = 0.f;
        for (int j = 0; j < 64; j++) s += __expf(sc[i][j] - m);
        rmax[i] = m;
        rsum[i] = s;
    }
    __syncthreads();
    const int lid = tid & 63;
    const int grp = tid >> 6;
    f16* __restrict__ apT = aT + (size_t)(q * Bsz + b) * 4096;
    f16* __restrict__ opR = oP + (size_t)(q * Bsz + b) * 4096;
    for (int i = grp; i < 64; i += 4) {  // oP row i, lanes over j
        const float v = __expf(sc[i][lid] - rmax[i]) / rsum[i];
        opR[i * 64 + lid] = (f16)v;
    }
    for (int jj = grp; jj < 64; jj += 4) {  // aT row jj, lanes over i (sc col read: 2-way, free)
        const float v = __expf(sc[lid][jj] - cmax[jj]) / csum[jj];
        apT[jj * 64 + lid] = (f16)v;
    }
}

// ---------------------------------------------------------------------------
// G GEMMs: per (b, term): G[o][t] = sum_d Wchunk[o,d] * X[t,d]
//   term = q*2 + part; part0: X = anchor (proj0); part1: X = other_q (proj1/2)
//   Wchunk = Wbh[:, q*512 + part*256 : +256]  (row-major, k-contiguous)
// Both operands k-contiguous -> direct-global MFMA fragments. One wave per term.
// Output G[b][term][o][t] f16 row-major.
__global__ __launch_bounds__(256) void g_gemm(const f16* __restrict__ proj,
                                              const f16* __restrict__ Wbh,
                                              f16* __restrict__ G) {
    const int b = blockIdx.x;
    const int tid = threadIdx.x, lane = tid & 63, w = tid >> 6;
    const int q = w >> 1, part = w & 1;
    const int z = part ? (1 + q) : 0;
    const f16* __restrict__ X = proj + ((size_t)z * MROWS + b * 64) * 256;  // [t][256]
    const f16* __restrict__ Wc = Wbh + q * 512 + part * 256;                // rows stride 1024
    const int lr = lane & 15, lk = lane >> 4;

    f32x4 acc[4][4];  // [o-frag][t-frag]
#pragma unroll
    for (int i = 0; i < 4; i++)
#pragma unroll
        for (int j = 0; j < 4; j++) acc[i][j] = (f32x4){0.f, 0.f, 0.f, 0.f};

    for (int ks = 0; ks < 8; ks++) {  // K=256 in steps of 32
        f16x8v af[4], bf[4];
#pragma unroll
        for (int mi = 0; mi < 4; mi++)
            af[mi] = *(const f16x8v*)(Wc + (size_t)(mi * 16 + lr) * FIN + ks * 32 + lk * 8);
#pragma unroll
        for (int nj = 0; nj < 4; nj++)
            bf[nj] = *(const f16x8v*)(X + (size_t)(nj * 16 + lr) * 256 + ks * 32 + lk * 8);
#pragma unroll
        for (int mi = 0; mi < 4; mi++)
#pragma unroll
            for (int nj = 0; nj < 4; nj++)
                acc[mi][nj] = __builtin_amdgcn_mfma_f32_16x16x32_f16(af[mi], bf[nj], acc[mi][nj], 0, 0, 0);
    }

    // stage per-wave 64x64 tile in LDS, then coalesced uint4 stores
    __shared__ __align__(16) f16 Gs[4][4096];
#pragma unroll
    for (int mi = 0; mi < 4; mi++)
#pragma unroll
        for (int nj = 0; nj < 4; nj++)
#pragma unroll
            for (int r = 0; r < 4; r++)
                Gs[w][(mi * 16 + lk * 4 + r) * 64 + nj * 16 + lr] = (f16)acc[mi][nj][r];
    __syncthreads();
#pragma unroll
    for (int r = 0; r < 8; r++) {
        const int u = r * 64 + lane;  // 512 16B-units per wave tile
        *(uint4*)(G + ((size_t)(b * 4 + w)) * 4096 + u * 8) = *(const uint4*)&Gs[w][u * 8];
    }
}

// ---------------------------------------------------------------------------
// Final fused attention-contraction + bias + LayerNorm + ReLU.
// h[b,s,o] = sum_term ( sum_k A_term[s,k]*G_term[o,k] + G_term[o,s] ) + bb[o]
//   term0: A = aT(q0) ; term1: A = oP(q0) ; term2: A = aT(q1) ; term3: A = oP(q1)
// Block = one b. 4 waves; wave w owns rows s in [16w,16w+16) x all 64 o.
// G tiles staged in LDS with XOR-swizzled 16B units for conflict-free B-frags.
__global__ __launch_bounds__(256) void attn_ln(const f16* __restrict__ aT,
                                               const f16* __restrict__ oP,
                                               const f16* __restrict__ G,
                                               const float* __restrict__ bb,
                                               const float* __restrict__ gamma,
                                               const float* __restrict__ beta,
                                               float* __restrict__ out) {
    const int b = blockIdx.x;
    const int tid = threadIdx.x, lane = tid & 63, w = tid >> 6;
    const int lr = lane & 15, lk = lane >> 4;

    __shared__ __align__(16) f16 Gs[4][4096];  // [term][swizzled 512 units x 8 f16]
    // stage: unit u holds G[o = u>>3][t = (u&7)*8 .. +8], stored at su = o*8 + ((u&7) ^ (o&7))
#pragma unroll
    for (int r = 0; r < 8; r++) {
        const int gu = r * 256 + tid;          // 0..2047
        const int term = gu >> 9, u = gu & 511;
        const int o = u >> 3, tch = u & 7;
        uint4 v = *(const uint4*)(G + ((size_t)(b * 4 + term)) * 4096 + u * 8);
        const int su = o * 8 + (tch ^ (o & 7));
        *(uint4*)&Gs[term][su * 8] = v;
    }
    __syncthreads();

    f32x4 acc[4];
#pragma unroll
    for (int j = 0; j < 4; j++) acc[j] = (f32x4){0.f, 0.f, 0.f, 0.f};

#pragma unroll
    for (int term = 0; term < 4; term++) {
        const int q = term >> 1;
        const f16* __restrict__ Abase =
            ((term & 1) ? oP : aT) + ((size_t)(q * Bsz + b)) * 4096;
#pragma unroll
        for (int kh = 0; kh < 2; kh++) {
            f16x8v af = *(const f16x8v*)(Abase + (size_t)(w * 16 + lr) * 64 + kh * 32 + lk * 8);
#pragma unroll
            for (int jf = 0; jf < 4; jf++) {
                const int o = jf * 16 + lr;
                const int su = o * 8 + ((kh * 4 + lk) ^ (o & 7));
                f16x8v bf = *(const f16x8v*)&Gs[term][su * 8];
                acc[jf] = __builtin_amdgcn_mfma_f32_16x16x32_f16(af, bf, acc[jf], 0, 0, 0);
            }
        }
    }

    float bbv[4], gv[4], bv2[4];
#pragma unroll
    for (int jf = 0; jf < 4; jf++) {
        const int o = jf * 16 + lr;
        bbv[jf] = bb[o];
        gv[jf] = gamma[o];
        bv2[jf] = beta[o];
    }
#pragma unroll
    for (int r = 0; r < 4; r++) {
        const int s = w * 16 + lk * 4 + r;
        float h[4];
        float s1 = 0.f, s2 = 0.f;
#pragma unroll
        for (int jf = 0; jf < 4; jf++) {
            const int o = jf * 16 + lr;
            float resid = 0.f;
#pragma unroll
            for (int term = 0; term < 4; term++) {
                const int su = o * 8 + ((s >> 3) ^ (o & 7));
                resid += (float)Gs[term][su * 8 + (s & 7)];
            }
            h[jf] = acc[jf][r] + resid + bbv[jf];
            s1 += h[jf];
            s2 += h[jf] * h[jf];
        }
#pragma unroll
        for (int m = 1; m < 16; m <<= 1) {
            s1 += __shfl_xor(s1, m);
            s2 += __shfl_xor(s2, m);
        }
        const float mu = s1 * (1.f / 64.f);
        const float inv = rsqrtf(s2 * (1.f / 64.f) - mu * mu + 1e-5f);
#pragma unroll
        for (int jf = 0; jf < 4; jf++) {
            const float v = (h[jf] - mu) * inv * gv[jf] + bv2[jf];
            out[(size_t)(b * 64 + s) * 64 + jf * 16 + lr] = fmaxf(v, 0.f);
        }
    }
}

extern "C" void kernel_launch(void* const* d_in, const int* in_sizes, int n_in,
                              void* d_out, int out_size, void* d_ws, size_t ws_size,
                              hipStream_t stream) {
    const float* latent0 = (const float*)d_in[0];
    const float* Wp0 = (const float*)d_in[1];
    const float* bp0 = (const float*)d_in[2];
    const float* latent1 = (const float*)d_in[3];
    const float* Wp1 = (const float*)d_in[4];
    const float* bp1 = (const float*)d_in[5];
    const float* latent2 = (const float*)d_in[6];
    const float* Wp2 = (const float*)d_in[7];
    const float* bp2 = (const float*)d_in[8];
    const float* corr = (const float*)d_in[9];
    const float* Wb = (const float*)d_in[10];
    const float* bb = (const float*)d_in[11];
    const float* gamma = (const float*)d_in[12];
    const float* beta = (const float*)d_in[13];

    char* ws = (char*)d_ws;
    f16* proj_h = (f16*)ws;                               // 3 * 16 MB
    f16* ac_h = (f16*)(ws + 48ull * 1024 * 1024);         // 16 MB
    f16* aT = (f16*)(ws + 64ull * 1024 * 1024);           // 8 MB  [2][512][64][64]
    f16* oP = (f16*)(ws + 72ull * 1024 * 1024);           // 8 MB  [2][512][64][64]
    f16* G = (f16*)(ws + 80ull * 1024 * 1024);            // 16 MB [512][4][64][64]
    f16* Wph = (f16*)(ws + 160ull * 1024 * 1024);         // 1.125 MB
    f16* corrT = (f16*)(ws + 162ull * 1024 * 1024);       // 128 KB
    f16* Wbh = (f16*)(ws + 162ull * 1024 * 1024 + 128ull * 1024);  // 128 KB

    float* out = (float*)d_out;
    dim3 blk(256);

    // pre-convert weights
    prep<<<2304, blk, 0, stream>>>(Wp0, Wp1, Wp2, corr, Wb, Wph, corrT, Wbh);

    // projections: proj_h[z] = latent_z @ Wp_z^T + bp_z   (fp16 MFMA, pipelined)
    mfma_gemm<false, true><<<dim3(2, 256, 3), blk, 0, stream>>>(
        latent0, latent1, latent2, (const f16*)nullptr, Wph, bp0, bp1, bp2, proj_h, Esz);

    // ac = proj0 @ corr  (B = corrT [e][d] f16)
    mfma_gemm<true, false><<<dim3(2, 256, 1), blk, 0, stream>>>(
        (const float*)nullptr, (const float*)nullptr, (const float*)nullptr, proj_h,
        corrT, (const float*)nullptr, (const float*)nullptr, (const float*)nullptr,
        ac_h, Dsz);

    const f16* proj1_h = proj_h + (size_t)MROWS * 256;
    const f16* proj2_h = proj_h + 2ull * MROWS * 256;

    // cc (MFMA) + both softmaxes -> aT (transposed) and oP (row-major), f16
    cc_softmax<<<dim3(Bsz, 2), blk, 0, stream>>>(ac_h, proj1_h, proj2_h, aT, oP);

    // G[b][term] = Wb_chunk @ X^T  (both operands row-major k-contiguous)
    g_gemm<<<Bsz, blk, 0, stream>>>(proj_h, Wbh, G);

    // fused attention contraction + bias + LayerNorm + ReLU
    attn_ln<<<Bsz, blk, 0, stream>>>(aT, oP, G, bb, gamma, beta, out);

    (void)in_sizes; (void)n_in; (void)out_size; (void)ws_size;
}

// Round 3
// 396.568 us; speedup vs baseline: 1.2659x; 1.2659x over previous
//
#include <hip/hip_runtime.h>
#include <hip/hip_bf16.h>
#include <stdint.h>

#define Bsz 512
#define Ssz 64
#define Esz 768
#define Dsz 256
#define MROWS (Bsz * Ssz)   // 32768
#define FIN 1024

typedef _Float16 f16;
typedef f16 f16x4 __attribute__((ext_vector_type(4)));
typedef f16 f16x8v __attribute__((ext_vector_type(8)));
typedef float f32x4 __attribute__((ext_vector_type(4)));

// async 16B/lane global->LDS copy. LDS dest = wave-uniform base + lane*16.
__device__ __forceinline__ void async_copy16(const void* g, void* l) {
    __builtin_amdgcn_global_load_lds((const __attribute__((address_space(1))) uint32_t*)g,
                                     (__attribute__((address_space(3))) uint32_t*)l, 16, 0, 0);
}

// ---------------------------------------------------------------------------
// prep: Wp (3x[256][768] f32) -> f16; corr [256][256] f32 -> corrT f16 [e][d];
//       Wb [64][1024] f32 -> f16 (for the G GEMMs)
__global__ __launch_bounds__(256) void prep(const float* __restrict__ Wp0,
                                            const float* __restrict__ Wp1,
                                            const float* __restrict__ Wp2,
                                            const float* __restrict__ corr,
                                            const float* __restrict__ Wb,
                                            f16* __restrict__ Wph,
                                            f16* __restrict__ corrT,
                                            f16* __restrict__ Wbh) {
    const int t = blockIdx.x * 256 + threadIdx.x;
    if (t < 3 * 196608) {
        const int z = t / 196608, i = t % 196608;
        const float* W = (z == 0) ? Wp0 : (z == 1) ? Wp1 : Wp2;
        Wph[(size_t)z * 196608 + i] = (f16)W[i];
    }
    if (t < 65536) {
        const int d = t >> 8, e = t & 255;
        corrT[e * 256 + d] = (f16)corr[d * 256 + e];
        Wbh[t] = (f16)Wb[t];
    }
}

// ---------------------------------------------------------------------------
// MFMA GEMM: C[m,n] = sum_k A[m,k] * B[n,k]  (B given [N][K] row-major, f16)
// Output f16 [M][256]. Tile 128x128xBK64, 256 threads = 4 waves, wave 64x64.
// Staging is pure global_load_lds width-16 (async, no VGPR round-trip, no
// registers near barriers). LDS layout is linear in lane order as the HW
// requires; bank-conflict-free fragment reads come from XOR-swizzling the
// chunk index into the per-lane GLOBAL source address (and the same XOR at
// fragment read) — both-sides-or-neither, same involution.
//   A_F32 path: A staged raw f32 (32 KB), converted f32->f16 at fragment build.
//   A_F16 path: A staged f16 like B (16 KB).
// Unit = 16B. A_F32: unit(row,c) at row*16 + (c ^ (row&15)), c = k/4 (0..15).
// f16 tiles:  unit(row,u) at row*8  + (u ^ (row&7)),  u = k/8 (0..7).
template <bool A_F16, bool BIAS>
__global__ __launch_bounds__(256) void mfma_gemm(
    const float* __restrict__ A32a, const float* __restrict__ A32b,
    const float* __restrict__ A32c, const f16* __restrict__ A16,
    const f16* __restrict__ Bh, const float* __restrict__ biasA,
    const float* __restrict__ biasB, const float* __restrict__ biasC,
    f16* __restrict__ Ch, int K) {
    constexpr int LDS_BYTES = A_F16 ? 32768 : 49152;
    __shared__ __align__(16) char smem[LDS_BYTES];
    float* Af32 = (float*)smem;                              // A_F32: 2048 units (32 KB)
    f16* Af16 = (f16*)smem;                                  // A_F16: 1024 units (16 KB)
    f16* Bf = (f16*)(smem + (A_F16 ? 16384 : 32768));        // 1024 units (16 KB)
    f16* Ce = (f16*)smem;                                    // epilogue 32 KB

    const int tid = threadIdx.x;
    const int n0 = blockIdx.x * 128;
    const int m0 = blockIdx.y * 128;
    const int z = blockIdx.z;
    const float* A32 = (z == 0) ? A32a : (z == 1) ? A32b : A32c;
    const float* bias = (z == 0) ? biasA : (z == 1) ? biasB : biasC;
    const f16* Bz = Bh + (size_t)z * 256 * K;
    f16* Cz = Ch + (size_t)z * MROWS * 256;

    const int lane = tid & 63;
    const int w = tid >> 6;
    const int lr = lane & 15;
    const int lk = lane >> 4;
    const int ma = (w >> 1) * 4;  // wave's first m-sub (of 8)
    const int nb = (w & 1) * 4;   // wave's first n-sub (of 8)

    f32x4 acc[4][4];
#pragma unroll
    for (int i = 0; i < 4; i++)
#pragma unroll
        for (int j = 0; j < 4; j++) acc[i][j] = (f32x4){0.f, 0.f, 0.f, 0.f};

    for (int k0 = 0; k0 < K; k0 += 64) {
        __syncthreads();  // previous iter's fragment reads complete
        // stage A (async)
#pragma unroll
        for (int i = 0; i < (A_F16 ? 4 : 8); i++) {
            const int Ub = (w * (A_F16 ? 4 : 8) + i) * 64;
            const int U = Ub + lane;
            if constexpr (A_F16) {
                const int row = U >> 3, u = (U & 7) ^ (row & 7);
                async_copy16(A16 + (size_t)(m0 + row) * K + k0 + u * 8, Af16 + (size_t)Ub * 8);
            } else {
                const int row = U >> 4, c = (U & 15) ^ (row & 15);
                async_copy16(A32 + (size_t)(m0 + row) * K + k0 + c * 4, Af32 + (size_t)Ub * 4);
            }
        }
        // stage B (async)
#pragma unroll
        for (int i = 0; i < 4; i++) {
            const int Ub = (w * 4 + i) * 64;
            const int U = Ub + lane;
            const int row = U >> 3, u = (U & 7) ^ (row & 7);
            async_copy16(Bz + (size_t)(n0 + row) * K + k0 + u * 8, Bf + (size_t)Ub * 8);
        }
        __syncthreads();  // implicit vmcnt(0) drain -> staging complete
#pragma unroll
        for (int kh = 0; kh < 2; kh++) {
            f16x8v af[4], bf[4];
#pragma unroll
            for (int i = 0; i < 4; i++) {
                const int row = (ma + i) * 16 + lr;  // row&15 == lr
                if constexpr (A_F16) {
                    const int u = (kh * 4 + lk) ^ (row & 7);
                    af[i] = *(const f16x8v*)&Af16[(row * 8 + u) * 8];
                } else {
                    const int c = kh * 8 + lk * 2;
                    const float4 v1 = *(const float4*)&Af32[(row * 16 + (c ^ lr)) * 4];
                    const float4 v2 = *(const float4*)&Af32[(row * 16 + ((c + 1) ^ lr)) * 4];
                    f16x8v h;
                    h[0] = (f16)v1.x; h[1] = (f16)v1.y; h[2] = (f16)v1.z; h[3] = (f16)v1.w;
                    h[4] = (f16)v2.x; h[5] = (f16)v2.y; h[6] = (f16)v2.z; h[7] = (f16)v2.w;
                    af[i] = h;
                }
            }
#pragma unroll
            for (int j = 0; j < 4; j++) {
                const int row = (nb + j) * 16 + lr;
                const int u = (kh * 4 + lk) ^ (row & 7);
                bf[j] = *(const f16x8v*)&Bf[(row * 8 + u) * 8];
            }
#pragma unroll
            for (int i = 0; i < 4; i++)
#pragma unroll
                for (int j = 0; j < 4; j++)
                    acc[i][j] = __builtin_amdgcn_mfma_f32_16x16x32_f16(af[i], bf[j], acc[i][j], 0, 0, 0);
        }
    }

    // epilogue through LDS for coalesced stores. 128x128 f16 = 32 KB.
    __syncthreads();  // last fragment reads complete before overwrite
    const int cr = lane & 15, qr = lane >> 4;
    const int mwl = (w >> 1) * 64;
    const int nwl = (w & 1) * 64;
#pragma unroll
    for (int i = 0; i < 4; i++) {
#pragma unroll
        for (int j = 0; j < 4; j++) {
            const int col = nwl + j * 16 + cr;
            const float bv = BIAS ? bias[n0 + col] : 0.f;
#pragma unroll
            for (int r = 0; r < 4; r++) {
                const int row = mwl + i * 16 + qr * 4 + r;
                Ce[row * 128 + col] = (f16)(acc[i][j][r] + bv);
            }
        }
    }
    __syncthreads();
#pragma unroll
    for (int r = 0; r < 8; r++) {
        const int f = r * 256 + tid;
        const int row = f >> 4, c16 = f & 15;
        uint4 v = *(const uint4*)&Ce[row * 128 + c16 * 8];
        *(uint4*)(Cz + (size_t)(m0 + row) * 256 + n0 + c16 * 8) = v;
    }
}

// ---------------------------------------------------------------------------
// Per (b,q): cc[i,j] = sum_e ac[b,i,e]*other[b,j,e] via MFMA (f16 in, f32 acc),
// fragments read directly from global. Then both softmaxes.
// Outputs (f16): aT[q][b][j][i] = softmax_i(cc)[i,j]  (transposed!)
//                oP[q][b][i][j] = softmax_j(cc)[i,j]  (row-major)
__global__ __launch_bounds__(256) void cc_softmax(const f16* __restrict__ ac,
                                                  const f16* __restrict__ proj1,
                                                  const f16* __restrict__ proj2,
                                                  f16* __restrict__ aT,
                                                  f16* __restrict__ oP) {
    const int b = blockIdx.x, q = blockIdx.y;
    const f16* __restrict__ A = ac + (size_t)b * Ssz * Dsz;
    const f16* __restrict__ Bp = (q ? proj2 : proj1) + (size_t)b * Ssz * Dsz;
    __shared__ float sc[64][65];
    __shared__ float cmax[64], csum[64], rmax[64], rsum[64];
    const int tid = threadIdx.x;
    const int lane = tid & 63, w = tid >> 6;
    const int lr = lane & 15;   // row/col within 16-tile (A row, B col)
    const int lk = lane >> 4;   // k-quarter: k = 8*lk + 0..7 within K=32 step

    f32x4 acc[4];
#pragma unroll
    for (int j = 0; j < 4; j++) acc[j] = (f32x4){0.f, 0.f, 0.f, 0.f};

    const f16* __restrict__ Arow = A + (size_t)(w * 16 + lr) * Dsz + lk * 8;
    for (int ks = 0; ks < 8; ks++) {  // K=256 in steps of 32
        f16x8v af = *(const f16x8v*)(Arow + ks * 32);
        f16x8v bf[4];
#pragma unroll
        for (int j = 0; j < 4; j++)
            bf[j] = *(const f16x8v*)(Bp + (size_t)(j * 16 + lr) * Dsz + ks * 32 + lk * 8);
#pragma unroll
        for (int j = 0; j < 4; j++)
            acc[j] = __builtin_amdgcn_mfma_f32_16x16x32_f16(af, bf[j], acc[j], 0, 0, 0);
    }
    // C/D layout: col = lane&15, row = (lane>>4)*4 + r
#pragma unroll
    for (int j = 0; j < 4; j++)
#pragma unroll
        for (int r = 0; r < 4; r++) sc[w * 16 + lk * 4 + r][j * 16 + lr] = acc[j][r];
    __syncthreads();
    if (tid < 64) {
        const int j = tid;
        float m = -1e30f;
        for (int i = 0; i < 64; i++) m = fmaxf(m, sc[i][j]);
        float s = 0.f;
        for (int i = 0; i < 64; i++) s += __expf(sc[i][j] - m);
        cmax[j] = m;
        csum[j] = s;
    } else if (tid < 128) {
        const int i = tid - 64;
        float m = -1e30f;
        for (int j = 0; j < 64; j++) m = fmaxf(m, sc[i][j]);
        float s = 0.f;
        for (int j = 0; j < 64; j++) s += __expf(sc[i][j] - m);
        rmax[i] = m;
        rsum[i] = s;
    }
    __syncthreads();
    const int lid = tid & 63;
    const int grp = tid >> 6;
    f16* __restrict__ apT = aT + (size_t)(q * Bsz + b) * 4096;
    f16* __restrict__ opR = oP + (size_t)(q * Bsz + b) * 4096;
    for (int i = grp; i < 64; i += 4) {  // oP row i, lanes over j
        const float v = __expf(sc[i][lid] - rmax[i]) / rsum[i];
        opR[i * 64 + lid] = (f16)v;
    }
    for (int jj = grp; jj < 64; jj += 4) {  // aT row jj, lanes over i (sc col read: 2-way, free)
        const float v = __expf(sc[lid][jj] - cmax[jj]) / csum[jj];
        apT[jj * 64 + lid] = (f16)v;
    }
}

// ---------------------------------------------------------------------------
// G GEMMs: per (b, term): G[o][t] = sum_d Wchunk[o,d] * X[t,d]
//   term = q*2 + part; part0: X = anchor (proj0); part1: X = other_q (proj1/2)
//   Wchunk = Wbh[:, q*512 + part*256 : +256]  (row-major, k-contiguous)
// Both operands k-contiguous -> direct-global MFMA fragments. One wave per term.
// Output G[b][term][o][t] f16 row-major.
__global__ __launch_bounds__(256) void g_gemm(const f16* __restrict__ proj,
                                              const f16* __restrict__ Wbh,
                                              f16* __restrict__ G) {
    const int b = blockIdx.x;
    const int tid = threadIdx.x, lane = tid & 63, w = tid >> 6;
    const int q = w >> 1, part = w & 1;
    const int z = part ? (1 + q) : 0;
    const f16* __restrict__ X = proj + ((size_t)z * MROWS + b * 64) * 256;  // [t][256]
    const f16* __restrict__ Wc = Wbh + q * 512 + part * 256;                // rows stride 1024
    const int lr = lane & 15, lk = lane >> 4;

    f32x4 acc[4][4];  // [o-frag][t-frag]
#pragma unroll
    for (int i = 0; i < 4; i++)
#pragma unroll
        for (int j = 0; j < 4; j++) acc[i][j] = (f32x4){0.f, 0.f, 0.f, 0.f};

    for (int ks = 0; ks < 8; ks++) {  // K=256 in steps of 32
        f16x8v af[4], bf[4];
#pragma unroll
        for (int mi = 0; mi < 4; mi++)
            af[mi] = *(const f16x8v*)(Wc + (size_t)(mi * 16 + lr) * FIN + ks * 32 + lk * 8);
#pragma unroll
        for (int nj = 0; nj < 4; nj++)
            bf[nj] = *(const f16x8v*)(X + (size_t)(nj * 16 + lr) * 256 + ks * 32 + lk * 8);
#pragma unroll
        for (int mi = 0; mi < 4; mi++)
#pragma unroll
            for (int nj = 0; nj < 4; nj++)
                acc[mi][nj] = __builtin_amdgcn_mfma_f32_16x16x32_f16(af[mi], bf[nj], acc[mi][nj], 0, 0, 0);
    }

    // stage per-wave 64x64 tile in LDS, then coalesced uint4 stores
    __shared__ __align__(16) f16 Gs[4][4096];
#pragma unroll
    for (int mi = 0; mi < 4; mi++)
#pragma unroll
        for (int nj = 0; nj < 4; nj++)
#pragma unroll
            for (int r = 0; r < 4; r++)
                Gs[w][(mi * 16 + lk * 4 + r) * 64 + nj * 16 + lr] = (f16)acc[mi][nj][r];
    __syncthreads();
#pragma unroll
    for (int r = 0; r < 8; r++) {
        const int u = r * 64 + lane;  // 512 16B-units per wave tile
        *(uint4*)(G + ((size_t)(b * 4 + w)) * 4096 + u * 8) = *(const uint4*)&Gs[w][u * 8];
    }
}

// ---------------------------------------------------------------------------
// Final fused attention-contraction + bias + LayerNorm + ReLU.
// h[b,s,o] = sum_term ( sum_k A_term[s,k]*G_term[o,k] + G_term[o,s] ) + bb[o]
//   term0: A = aT(q0) ; term1: A = oP(q0) ; term2: A = aT(q1) ; term3: A = oP(q1)
// Block = one b. 4 waves; wave w owns rows s in [16w,16w+16) x all 64 o.
// G tiles staged in LDS with XOR-swizzled 16B units for conflict-free B-frags.
__global__ __launch_bounds__(256) void attn_ln(const f16* __restrict__ aT,
                                               const f16* __restrict__ oP,
                                               const f16* __restrict__ G,
                                               const float* __restrict__ bb,
                                               const float* __restrict__ gamma,
                                               const float* __restrict__ beta,
                                               float* __restrict__ out) {
    const int b = blockIdx.x;
    const int tid = threadIdx.x, lane = tid & 63, w = tid >> 6;
    const int lr = lane & 15, lk = lane >> 4;

    __shared__ __align__(16) f16 Gs[4][4096];  // [term][swizzled 512 units x 8 f16]
    // stage: unit u holds G[o = u>>3][t = (u&7)*8 .. +8], stored at su = o*8 + ((u&7) ^ (o&7))
#pragma unroll
    for (int r = 0; r < 8; r++) {
        const int gu = r * 256 + tid;          // 0..2047
        const int term = gu >> 9, u = gu & 511;
        const int o = u >> 3, tch = u & 7;
        uint4 v = *(const uint4*)(G + ((size_t)(b * 4 + term)) * 4096 + u * 8);
        const int su = o * 8 + (tch ^ (o & 7));
        *(uint4*)&Gs[term][su * 8] = v;
    }
    __syncthreads();

    f32x4 acc[4];
#pragma unroll
    for (int j = 0; j < 4; j++) acc[j] = (f32x4){0.f, 0.f, 0.f, 0.f};

#pragma unroll
    for (int term = 0; term < 4; term++) {
        const int q = term >> 1;
        const f16* __restrict__ Abase =
            ((term & 1) ? oP : aT) + ((size_t)(q * Bsz + b)) * 4096;
#pragma unroll
        for (int kh = 0; kh < 2; kh++) {
            f16x8v af = *(const f16x8v*)(Abase + (size_t)(w * 16 + lr) * 64 + kh * 32 + lk * 8);
#pragma unroll
            for (int jf = 0; jf < 4; jf++) {
                const int o = jf * 16 + lr;
                const int su = o * 8 + ((kh * 4 + lk) ^ (o & 7));
                f16x8v bf = *(const f16x8v*)&Gs[term][su * 8];
                acc[jf] = __builtin_amdgcn_mfma_f32_16x16x32_f16(af, bf, acc[jf], 0, 0, 0);
            }
        }
    }

    float bbv[4], gv[4], bv2[4];
#pragma unroll
    for (int jf = 0; jf < 4; jf++) {
        const int o = jf * 16 + lr;
        bbv[jf] = bb[o];
        gv[jf] = gamma[o];
        bv2[jf] = beta[o];
    }
#pragma unroll
    for (int r = 0; r < 4; r++) {
        const int s = w * 16 + lk * 4 + r;
        float h[4];
        float s1 = 0.f, s2 = 0.f;
#pragma unroll
        for (int jf = 0; jf < 4; jf++) {
            const int o = jf * 16 + lr;
            float resid = 0.f;
#pragma unroll
            for (int term = 0; term < 4; term++) {
                const int su = o * 8 + ((s >> 3) ^ (o & 7));
                resid += (float)Gs[term][su * 8 + (s & 7)];
            }
            h[jf] = acc[jf][r] + resid + bbv[jf];
            s1 += h[jf];
            s2 += h[jf] * h[jf];
        }
#pragma unroll
        for (int m = 1; m < 16; m <<= 1) {
            s1 += __shfl_xor(s1, m);
            s2 += __shfl_xor(s2, m);
        }
        const float mu = s1 * (1.f / 64.f);
        const float inv = rsqrtf(s2 * (1.f / 64.f) - mu * mu + 1e-5f);
#pragma unroll
        for (int jf = 0; jf < 4; jf++) {
            const float v = (h[jf] - mu) * inv * gv[jf] + bv2[jf];
            out[(size_t)(b * 64 + s) * 64 + jf * 16 + lr] = fmaxf(v, 0.f);
        }
    }
}

extern "C" void kernel_launch(void* const* d_in, const int* in_sizes, int n_in,
                              void* d_out, int out_size, void* d_ws, size_t ws_size,
                              hipStream_t stream) {
    const float* latent0 = (const float*)d_in[0];
    const float* Wp0 = (const float*)d_in[1];
    const float* bp0 = (const float*)d_in[2];
    const float* latent1 = (const float*)d_in[3];
    const float* Wp1 = (const float*)d_in[4];
    const float* bp1 = (const float*)d_in[5];
    const float* latent2 = (const float*)d_in[6];
    const float* Wp2 = (const float*)d_in[7];
    const float* bp2 = (const float*)d_in[8];
    const float* corr = (const float*)d_in[9];
    const float* Wb = (const float*)d_in[10];
    const float* bb = (const float*)d_in[11];
    const float* gamma = (const float*)d_in[12];
    const float* beta = (const float*)d_in[13];

    char* ws = (char*)d_ws;
    f16* proj_h = (f16*)ws;                               // 3 * 16 MB
    f16* ac_h = (f16*)(ws + 48ull * 1024 * 1024);         // 16 MB
    f16* aT = (f16*)(ws + 64ull * 1024 * 1024);           // 8 MB  [2][512][64][64]
    f16* oP = (f16*)(ws + 72ull * 1024 * 1024);           // 8 MB  [2][512][64][64]
    f16* G = (f16*)(ws + 80ull * 1024 * 1024);            // 16 MB [512][4][64][64]
    f16* Wph = (f16*)(ws + 160ull * 1024 * 1024);         // 1.125 MB
    f16* corrT = (f16*)(ws + 162ull * 1024 * 1024);       // 128 KB
    f16* Wbh = (f16*)(ws + 162ull * 1024 * 1024 + 128ull * 1024);  // 128 KB

    float* out = (float*)d_out;
    dim3 blk(256);

    // pre-convert weights
    prep<<<2304, blk, 0, stream>>>(Wp0, Wp1, Wp2, corr, Wb, Wph, corrT, Wbh);

    // projections: proj_h[z] = latent_z @ Wp_z^T + bp_z   (fp16 MFMA, async staging)
    mfma_gemm<false, true><<<dim3(2, 256, 3), blk, 0, stream>>>(
        latent0, latent1, latent2, (const f16*)nullptr, Wph, bp0, bp1, bp2, proj_h, Esz);

    // ac = proj0 @ corr  (B = corrT [e][d] f16)
    mfma_gemm<true, false><<<dim3(2, 256, 1), blk, 0, stream>>>(
        (const float*)nullptr, (const float*)nullptr, (const float*)nullptr, proj_h,
        corrT, (const float*)nullptr, (const float*)nullptr, (const float*)nullptr,
        ac_h, Dsz);

    const f16* proj1_h = proj_h + (size_t)MROWS * 256;
    const f16* proj2_h = proj_h + 2ull * MROWS * 256;

    // cc (MFMA) + both softmaxes -> aT (transposed) and oP (row-major), f16
    cc_softmax<<<dim3(Bsz, 2), blk, 0, stream>>>(ac_h, proj1_h, proj2_h, aT, oP);

    // G[b][term] = Wb_chunk @ X^T  (both operands row-major k-contiguous)
    g_gemm<<<Bsz, blk, 0, stream>>>(proj_h, Wbh, G);

    // fused attention contraction + bias + LayerNorm + ReLU
    attn_ln<<<Bsz, blk, 0, stream>>>(aT, oP, G, bb, gamma, beta, out);

    (void)in_sizes; (void)n_in; (void)out_size; (void)ws_size;
}